// Round 5
// baseline (121.046 us; speedup 1.0000x reference)
//
#include <hip/hip_runtime.h>

#define NODES 512
#define WORDS 16          // 512 bits / 32
#define NBATCH 32
#define SENTINEL 11       // MAX_DISTANCE + 1
#define NEMB 12           // MAX_DISTANCE + 2
#define NOUT 8
#define G 4               // sources per BFS block

// ---------------------------------------------------------------------------
// K1: pack adjacency bits, one u32 word (32 elements, 8x float4) per thread.
// Batch index is constant within a block -> node_mask (int32 on upload) is
// ballot-packed into LDS once per block (fuses the old mask_pack kernel).
// ---------------------------------------------------------------------------
__global__ void __launch_bounds__(256)
pack_bits(const float* __restrict__ A, const int* __restrict__ mask,
          unsigned int* __restrict__ bitA) {
    const int tid = blockIdx.x * 256 + threadIdx.x;   // 262144 words total
    const int t = threadIdx.x;
    const int w = tid & 15;
    const int i = (tid >> 4) & 511;
    const int b = tid >> 13;                          // constant per block

    __shared__ unsigned int s_mw[WORDS];
    // pack this batch's 512 mask values: 2 loads + 2 ballots per wave
    {
        bool m0 = mask[b * NODES + t] != 0;
        bool m1 = mask[b * NODES + 256 + t] != 0;
        unsigned long long b0 = __ballot(m0);
        unsigned long long b1 = __ballot(m1);
        if ((t & 63) == 0) {
            int wv = t >> 6;
            s_mw[2 * wv]         = (unsigned int)b0;
            s_mw[2 * wv + 1]     = (unsigned int)(b0 >> 32);
            s_mw[8 + 2 * wv]     = (unsigned int)b1;
            s_mw[8 + 2 * wv + 1] = (unsigned int)(b1 >> 32);
        }
    }

    const float4* p = (const float4*)(A + (size_t)tid * 32);
    unsigned int bits = 0;
#pragma unroll
    for (int q = 0; q < 8; ++q) {
        float4 v = p[q];
        bits |= (v.x > 0.5f ? 1u : 0u) << (4 * q);
        bits |= (v.y > 0.5f ? 1u : 0u) << (4 * q + 1);
        bits |= (v.z > 0.5f ? 1u : 0u) << (4 * q + 2);
        bits |= (v.w > 0.5f ? 1u : 0u) << (4 * q + 3);
    }
    __syncthreads();
    bool rv = (s_mw[i >> 5] >> (i & 31)) & 1u;
    bitA[tid] = rv ? (bits & s_mw[w]) : 0u;
}

// ---------------------------------------------------------------------------
// K2: symmetrize: adj[b,i,w] |= transpose bits (1 MB, L2-resident).
// ---------------------------------------------------------------------------
__global__ void __launch_bounds__(256)
symmetrize(const unsigned int* __restrict__ bitA, unsigned int* __restrict__ adjb) {
    int tid = blockIdx.x * 256 + threadIdx.x;   // total B*N*WORDS = 262144
    int w = tid & 15;
    int i = (tid >> 4) & 511;
    int b = tid >> 13;
    const unsigned int* base = bitA + (size_t)b * NODES * WORDS;
    unsigned int word = base[i * WORDS + w];
    unsigned int t = 0;
    int iw = i >> 5, ib = i & 31;
#pragma unroll
    for (int k = 0; k < 32; ++k) {
        t |= ((base[(32 * w + k) * WORDS + iw] >> ib) & 1u) << k;
    }
    adjb[tid] = word | t;
}

// ---------------------------------------------------------------------------
// K3: fused bitset-BFS + embedding store. Block = (G=4 sources, batch),
// 512 threads; thread j holds symmetric adjacency row j (16 VGPRs).
// Double-buffered frontier -> ONE barrier per hop. Early exit both on
// "no new nodes" AND on saturation (all valid nodes reached) which skips
// the confirming round. uint4 LDS frontier reads. VGPR capped at 64 for
// 4 blocks/CU so neighbor blocks' stores hide this block's BFS phase.
// ---------------------------------------------------------------------------
__global__ void __launch_bounds__(512, 8)
bfs_store(const unsigned int* __restrict__ adjb, const int* __restrict__ mask,
          const float* __restrict__ emb, float4* __restrict__ out4) {
    const int i0 = blockIdx.x * G;
    const int b = blockIdx.y;
    const int j = threadIdx.x;

    __shared__ unsigned int s_f[2][G][WORDS];
    __shared__ unsigned int s_state[2][8];     // per-wave: bit0 anyNew, bit1 allDone
    __shared__ unsigned char s_dist[G][NODES];
    __shared__ __align__(16) float s_emb[NEMB * NOUT];

    if (j < NEMB * NOUT) s_emb[j] = emb[j];

    // adjacency row j (64 B)
    const uint4* rowp = (const uint4*)(adjb + ((size_t)b * NODES + j) * WORDS);
    uint4 ar[4];
    ar[0] = rowp[0]; ar[1] = rowp[1]; ar[2] = rowp[2]; ar[3] = rowp[3];

    const bool valid_j = (mask[b * NODES + j] != 0);

    if (j < G * WORDS) {
        int s = j >> 4, w = j & 15;
        int i = i0 + s;
        bool v = (mask[b * NODES + i] != 0);
        s_f[0][s][w] = (v && (i >> 5) == w) ? (1u << (i & 31)) : 0u;
    }

    int dist[G];
    bool reach[G];
#pragma unroll
    for (int s = 0; s < G; ++s) {
        int i = i0 + s;
        reach[s] = (j == i) && valid_j;   // j==i -> valid_j == valid_i
        dist[s] = reach[s] ? 0 : SENTINEL;
    }
    __syncthreads();

    int p = 0;
    for (int t = 1; t <= 10; ++t) {
        bool newly[G];
#pragma unroll
        for (int s = 0; s < G; ++s) {
            const uint4* f4 = (const uint4*)s_f[p][s];
            uint4 f0 = f4[0], f1 = f4[1], f2 = f4[2], f3 = f4[3];
            unsigned int hit =
                (ar[0].x & f0.x) | (ar[0].y & f0.y) | (ar[0].z & f0.z) | (ar[0].w & f0.w) |
                (ar[1].x & f1.x) | (ar[1].y & f1.y) | (ar[1].z & f1.z) | (ar[1].w & f1.w) |
                (ar[2].x & f2.x) | (ar[2].y & f2.y) | (ar[2].z & f2.z) | (ar[2].w & f2.w) |
                (ar[3].x & f3.x) | (ar[3].y & f3.y) | (ar[3].z & f3.z) | (ar[3].w & f3.w);
            newly[s] = (hit != 0) && !reach[s];
        }
        unsigned long long anyb = 0;
        unsigned long long doneb = ~0ull;
#pragma unroll
        for (int s = 0; s < G; ++s) {
            unsigned long long bal = __ballot(newly[s]);
            anyb |= bal;
            if (newly[s]) { reach[s] = true; dist[s] = t; }
            doneb &= __ballot(reach[s] || !valid_j);
            if ((j & 63) == 0) {
                int wv = j >> 6;
                s_f[p ^ 1][s][2 * wv]     = (unsigned int)bal;
                s_f[p ^ 1][s][2 * wv + 1] = (unsigned int)(bal >> 32);
            }
        }
        if ((j & 63) == 0) {
            s_state[p ^ 1][j >> 6] =
                ((anyb != 0ull) ? 1u : 0u) | ((doneb == ~0ull) ? 2u : 0u);
        }
        __syncthreads();   // next frontier + state visible; old buffer now free
        p ^= 1;
        unsigned int anyw = 0, donew = 2;
#pragma unroll
        for (int wv = 0; wv < 8; ++wv) {
            unsigned int st = s_state[p][wv];
            anyw |= st;
            donew &= st;
        }
        if (!(anyw & 1u) || (donew & 2u)) break;
    }

    // Epilogue: redistribute dist via LDS; 8 lane-contiguous float4 stores.
#pragma unroll
    for (int s = 0; s < G; ++s) s_dist[s][j] = (unsigned char)dist[s];
    __syncthreads();   // also orders the s_emb writes from kernel start

    const float4* e4 = (const float4*)s_emb;
#pragma unroll
    for (int s = 0; s < G; ++s) {
        size_t rb = ((size_t)b * NODES + (i0 + s)) * (NODES * NOUT / 4); // 1024 f4/row
#pragma unroll
        for (int h = 0; h < 2; ++h) {
            int d = s_dist[s][(h << 8) + (j >> 1)];   // dist of column (h*512+j)/2
            out4[rb + h * NODES + j] = e4[2 * d + (j & 1)];
        }
    }
}

// ---------------------------------------------------------------------------
extern "C" void kernel_launch(void* const* d_in, const int* in_sizes, int n_in,
                              void* d_out, int out_size, void* d_ws, size_t ws_size,
                              hipStream_t stream) {
    const float* adjacency = (const float*)d_in[0];
    const int* node_mask = (const int*)d_in[1];   // bool -> int32 on upload
    const float* emb = (const float*)d_in[2];
    float4* out4 = (float4*)d_out;

    unsigned int* bitA = (unsigned int*)d_ws;                       // 1 MB
    unsigned int* adjb = bitA + (size_t)NBATCH * NODES * WORDS;     // 1 MB

    // K1: 262144 words -> 1024 blocks (each thread packs 32 adjacency elems)
    pack_bits<<<1024, 256, 0, stream>>>(adjacency, node_mask, bitA);
    // K2: 262144 words -> 1024 blocks
    symmetrize<<<1024, 256, 0, stream>>>(bitA, adjb);
    // K3: one block per (4 sources, batch); fused BFS + store
    bfs_store<<<dim3(NODES / G, NBATCH), 512, 0, stream>>>(adjb, node_mask, emb, out4);
}

// Round 6
// 80.493 us; speedup vs baseline: 1.5038x; 1.5038x over previous
//
#include <hip/hip_runtime.h>

#define NODES 512
#define WORDS 16          // 512 bits / 32
#define NBATCH 32
#define SENTINEL 11       // MAX_DISTANCE + 1
#define NEMB 12           // MAX_DISTANCE + 2
#define NOUT 8
#define G 4               // sources per BFS block

// ---------------------------------------------------------------------------
// K1: pack adjacency bits, one u32 word (32 elements, 8x float4) per thread.
// Batch index is constant within a block -> node_mask (int32 on upload) is
// ballot-packed into LDS once per block (fuses the old mask_pack kernel).
// ---------------------------------------------------------------------------
__global__ void __launch_bounds__(256)
pack_bits(const float* __restrict__ A, const int* __restrict__ mask,
          unsigned int* __restrict__ bitA) {
    const int tid = blockIdx.x * 256 + threadIdx.x;   // 262144 words total
    const int t = threadIdx.x;
    const int w = tid & 15;
    const int i = (tid >> 4) & 511;
    const int b = tid >> 13;                          // constant per block

    __shared__ unsigned int s_mw[WORDS];
    // pack this batch's 512 mask values: 2 loads + 2 ballots per wave
    {
        bool m0 = mask[b * NODES + t] != 0;
        bool m1 = mask[b * NODES + 256 + t] != 0;
        unsigned long long b0 = __ballot(m0);
        unsigned long long b1 = __ballot(m1);
        if ((t & 63) == 0) {
            int wv = t >> 6;
            s_mw[2 * wv]         = (unsigned int)b0;
            s_mw[2 * wv + 1]     = (unsigned int)(b0 >> 32);
            s_mw[8 + 2 * wv]     = (unsigned int)b1;
            s_mw[8 + 2 * wv + 1] = (unsigned int)(b1 >> 32);
        }
    }

    const float4* p = (const float4*)(A + (size_t)tid * 32);
    unsigned int bits = 0;
#pragma unroll
    for (int q = 0; q < 8; ++q) {
        float4 v = p[q];
        bits |= (v.x > 0.5f ? 1u : 0u) << (4 * q);
        bits |= (v.y > 0.5f ? 1u : 0u) << (4 * q + 1);
        bits |= (v.z > 0.5f ? 1u : 0u) << (4 * q + 2);
        bits |= (v.w > 0.5f ? 1u : 0u) << (4 * q + 3);
    }
    __syncthreads();
    bool rv = (s_mw[i >> 5] >> (i & 31)) & 1u;
    bitA[tid] = rv ? (bits & s_mw[w]) : 0u;
}

// ---------------------------------------------------------------------------
// K2: symmetrize: adj[b,i,w] |= transpose bits (1 MB, L2-resident).
// ---------------------------------------------------------------------------
__global__ void __launch_bounds__(256)
symmetrize(const unsigned int* __restrict__ bitA, unsigned int* __restrict__ adjb) {
    int tid = blockIdx.x * 256 + threadIdx.x;   // total B*N*WORDS = 262144
    int w = tid & 15;
    int i = (tid >> 4) & 511;
    int b = tid >> 13;
    const unsigned int* base = bitA + (size_t)b * NODES * WORDS;
    unsigned int word = base[i * WORDS + w];
    unsigned int t = 0;
    int iw = i >> 5, ib = i & 31;
#pragma unroll
    for (int k = 0; k < 32; ++k) {
        t |= ((base[(32 * w + k) * WORDS + iw] >> ib) & 1u) << k;
    }
    adjb[tid] = word | t;
}

// ---------------------------------------------------------------------------
// K3: fused bitset-BFS + embedding store. Block = (G=4 sources, batch),
// 512 threads; thread j holds symmetric adjacency row j (16 VGPRs).
// Double-buffered frontier -> ONE barrier per hop. Early exit on "no new
// nodes" AND on saturation (all valid nodes reached; skips confirm round).
// __launch_bounds__(512,4): cap 128 VGPR (live set fits, NO spills — the
// (512,8)=64-VGPR cap in round 5 spilled and cost +35us) -> 2 blocks/CU.
// ---------------------------------------------------------------------------
__global__ void __launch_bounds__(512, 4)
bfs_store(const unsigned int* __restrict__ adjb, const int* __restrict__ mask,
          const float* __restrict__ emb, float4* __restrict__ out4) {
    const int i0 = blockIdx.x * G;
    const int b = blockIdx.y;
    const int j = threadIdx.x;

    __shared__ unsigned int s_f[2][G][WORDS];
    __shared__ unsigned int s_state[2][8];     // per-wave: bit0 anyNew, bit1 allDone
    __shared__ unsigned char s_dist[G][NODES];
    __shared__ __align__(16) float s_emb[NEMB * NOUT];

    if (j < NEMB * NOUT) s_emb[j] = emb[j];

    // adjacency row j (64 B)
    const uint4* rowp = (const uint4*)(adjb + ((size_t)b * NODES + j) * WORDS);
    uint4 ar[4];
    ar[0] = rowp[0]; ar[1] = rowp[1]; ar[2] = rowp[2]; ar[3] = rowp[3];

    const bool valid_j = (mask[b * NODES + j] != 0);

    if (j < G * WORDS) {
        int s = j >> 4, w = j & 15;
        int i = i0 + s;
        bool v = (mask[b * NODES + i] != 0);
        s_f[0][s][w] = (v && (i >> 5) == w) ? (1u << (i & 31)) : 0u;
    }

    int dist[G];
    bool reach[G];
#pragma unroll
    for (int s = 0; s < G; ++s) {
        int i = i0 + s;
        reach[s] = (j == i) && valid_j;   // j==i -> valid_j == valid_i
        dist[s] = reach[s] ? 0 : SENTINEL;
    }
    __syncthreads();

    int p = 0;
    for (int t = 1; t <= 10; ++t) {
        bool newly[G];
#pragma unroll
        for (int s = 0; s < G; ++s) {
            const uint4* f4 = (const uint4*)s_f[p][s];
            uint4 f0 = f4[0], f1 = f4[1], f2 = f4[2], f3 = f4[3];
            unsigned int hit =
                (ar[0].x & f0.x) | (ar[0].y & f0.y) | (ar[0].z & f0.z) | (ar[0].w & f0.w) |
                (ar[1].x & f1.x) | (ar[1].y & f1.y) | (ar[1].z & f1.z) | (ar[1].w & f1.w) |
                (ar[2].x & f2.x) | (ar[2].y & f2.y) | (ar[2].z & f2.z) | (ar[2].w & f2.w) |
                (ar[3].x & f3.x) | (ar[3].y & f3.y) | (ar[3].z & f3.z) | (ar[3].w & f3.w);
            newly[s] = (hit != 0) && !reach[s];
        }
        unsigned long long anyb = 0;
        unsigned long long doneb = ~0ull;
#pragma unroll
        for (int s = 0; s < G; ++s) {
            unsigned long long bal = __ballot(newly[s]);
            anyb |= bal;
            if (newly[s]) { reach[s] = true; dist[s] = t; }
            doneb &= __ballot(reach[s] || !valid_j);
            if ((j & 63) == 0) {
                int wv = j >> 6;
                s_f[p ^ 1][s][2 * wv]     = (unsigned int)bal;
                s_f[p ^ 1][s][2 * wv + 1] = (unsigned int)(bal >> 32);
            }
        }
        if ((j & 63) == 0) {
            s_state[p ^ 1][j >> 6] =
                ((anyb != 0ull) ? 1u : 0u) | ((doneb == ~0ull) ? 2u : 0u);
        }
        __syncthreads();   // next frontier + state visible; old buffer now free
        p ^= 1;
        unsigned int anyw = 0, donew = 2;
#pragma unroll
        for (int wv = 0; wv < 8; ++wv) {
            unsigned int st = s_state[p][wv];
            anyw |= st;
            donew &= st;
        }
        if (!(anyw & 1u) || (donew & 2u)) break;
    }

    // Epilogue: redistribute dist via LDS; 8 lane-contiguous float4 stores.
#pragma unroll
    for (int s = 0; s < G; ++s) s_dist[s][j] = (unsigned char)dist[s];
    __syncthreads();   // also orders the s_emb writes from kernel start

    const float4* e4 = (const float4*)s_emb;
#pragma unroll
    for (int s = 0; s < G; ++s) {
        size_t rb = ((size_t)b * NODES + (i0 + s)) * (NODES * NOUT / 4); // 1024 f4/row
#pragma unroll
        for (int h = 0; h < 2; ++h) {
            int d = s_dist[s][(h << 8) + (j >> 1)];   // dist of column (h*512+j)/2
            out4[rb + h * NODES + j] = e4[2 * d + (j & 1)];
        }
    }
}

// ---------------------------------------------------------------------------
extern "C" void kernel_launch(void* const* d_in, const int* in_sizes, int n_in,
                              void* d_out, int out_size, void* d_ws, size_t ws_size,
                              hipStream_t stream) {
    const float* adjacency = (const float*)d_in[0];
    const int* node_mask = (const int*)d_in[1];   // bool -> int32 on upload
    const float* emb = (const float*)d_in[2];
    float4* out4 = (float4*)d_out;

    unsigned int* bitA = (unsigned int*)d_ws;                       // 1 MB
    unsigned int* adjb = bitA + (size_t)NBATCH * NODES * WORDS;     // 1 MB

    // K1: 262144 words -> 1024 blocks (each thread packs 32 adjacency elems)
    pack_bits<<<1024, 256, 0, stream>>>(adjacency, node_mask, bitA);
    // K2: 262144 words -> 1024 blocks
    symmetrize<<<1024, 256, 0, stream>>>(bitA, adjb);
    // K3: one block per (4 sources, batch); fused BFS + store
    bfs_store<<<dim3(NODES / G, NBATCH), 512, 0, stream>>>(adjb, node_mask, emb, out4);
}